// Round 1
// baseline (226.357 us; speedup 1.0000x reference)
//
#include <hip/hip_runtime.h>
#include <hip/hip_cooperative_groups.h>

namespace cg = cooperative_groups;

// Problem constants (reference: B,T,D,O = 16,1024,1024,10; T==D required)
#define BB 16
#define TT 1024
#define DD 1024
#define OO 10

// ---------------------------------------------------------------------------
// R(this): eliminate d_ws entirely. rocprof showed the timed graph contains
// two 256 MiB __amd_rocclr_fillBufferAligned dispatches (41 us each) = the
// harness re-poisoning the workspace; 2x41 + 2x19.5 (gemm passes) = 121 us.
// u (B*O*T floats = 655 KB) is EXACTLY the size/layout of the output buffer,
// so: single cooperative kernel, u staged in d_out, two grid.sync()s:
//   sync#1: all u[b,o,t] written  -> before any block stages the u-slab
//   sync#2: all slab stage-reads done -> before any block overwrites with out
// Gemm body = R5/R10 proven mapping, UNCHANGED: 4 waves, 32 rows/block;
// operand (W or u-slab) in LDS [o][t4] read as 8-address broadcast float4;
// lane l of group g of wave w: rows t0+g+8j, d = w*256+it*32+l*4; depth-2
// prefetch; unroll-1 outer; 8-lane dots -> 3 __shfl_down(8) + LDS combine.
//
// Refuted (do not retry): occupancy-hint bounds (R2 spill), per-chunk LDS
// staging barriers (R6), device-barrier fusion as a KERNEL-TIME opt (R8 --
// it kept d_ws so the poison fills stayed), per-block softmax fold (R9),
// non-temporal X loads (R11), depth-4 prefetch (R12), 8-wave blocks (R13).
// Co-residency: 512 blocks, need 2/CU; LDS 46.1 KB -> 3 fit; VGPR << 256. OK.
// ---------------------------------------------------------------------------
__global__ __launch_bounds__(256) void fused_kernel(
    const float* __restrict__ X,     // (B,T,D) logits
    const float* __restrict__ W,     // (O,D)
    const float* __restrict__ bias,  // (O)
    float* __restrict__ Y)           // (B,O,T) out; also holds u transiently
{
    cg::grid_group gg = cg::this_grid();

    __shared__ float4 sW4[OO * 256];    // 40 KB operand ([o][t4])
    __shared__ float  part[4][32][OO];  // 5 KB
    __shared__ float  zred[OO];         // 40 B softmax denom

    const int b   = blockIdx.y;
    const int t0  = blockIdx.x * 32;
    const int tid = threadIdx.x;

    const int w    = tid >> 6;       // wave 0..3 -> d quarter
    const int lane = tid & 63;
    const int l    = lane & 7;       // d-slice within row
    const int g    = lane >> 3;      // row group 0..7
    const int dofs = w * 256 + l * 4;

    const float* xp[4];
#pragma unroll
    for (int j = 0; j < 4; ++j)
        xp[j] = X + ((size_t)b * TT + t0 + g + 8 * j) * DD + dofs;
    const float* sWl = (const float*)sW4 + dofs;
    float* const uslab = Y + (size_t)b * OO * TT;  // u lives in the out buffer

#pragma unroll
    for (int phase = 0; phase < 2; ++phase) {
        // ---- stage operand -> LDS (2560 float4, contiguous, coalesced) ----
        {
            const float4* src = (phase == 0) ? (const float4*)W
                                             : (const float4*)uslab;
#pragma unroll
            for (int c = 0; c < 10; ++c)
                sW4[c * 256 + tid] = src[c * 256 + tid];
        }
        __syncthreads();

        if (phase == 1) {
            // Z[b,o] = sum_t u from the staged slab. Wave w handles o = w+4k.
#pragma unroll
            for (int k = 0; k < 3; ++k) {
                const int o = w + 4 * k;
                if (o < OO) {
                    float s = 0.f;
#pragma unroll
                    for (int q = 0; q < 4; ++q) {
                        const float4 v = sW4[o * 256 + lane * 4 + q];
                        s += v.x + v.y + v.z + v.w;
                    }
#pragma unroll
                    for (int off = 32; off > 0; off >>= 1)
                        s += __shfl_down(s, off, 64);
                    if (lane == 0) zred[o] = s;
                }
            }
        }

        float acc[4][OO];
#pragma unroll
        for (int j = 0; j < 4; ++j)
#pragma unroll
            for (int o = 0; o < OO; ++o) acc[j][o] = 0.f;

        // 2-deep prefetch of the logits slices
        float4 x0[4], x1[4];
#pragma unroll
        for (int j = 0; j < 4; ++j) {
            x0[j] = *(const float4*)(xp[j]);
            x1[j] = *(const float4*)(xp[j] + 32);
        }

#pragma unroll 1
        for (int it = 0; it < 8; it += 2) {
            float4 c0[4];
#pragma unroll
            for (int j = 0; j < 4; ++j) c0[j] = x0[j];
            if (it < 6) {
#pragma unroll
                for (int j = 0; j < 4; ++j)
                    x0[j] = *(const float4*)(xp[j] + (it + 2) * 32);
            }
            {
                const float* wp = sWl + it * 32;
#pragma unroll
                for (int o = 0; o < OO; ++o) {
                    const float4 wv = *(const float4*)(wp + o * DD);
#pragma unroll
                    for (int j = 0; j < 4; ++j)
                        acc[j][o] += c0[j].x * wv.x + c0[j].y * wv.y +
                                     c0[j].z * wv.z + c0[j].w * wv.w;
                }
            }
#pragma unroll
            for (int j = 0; j < 4; ++j) c0[j] = x1[j];
            if (it < 5) {
#pragma unroll
                for (int j = 0; j < 4; ++j)
                    x1[j] = *(const float4*)(xp[j] + (it + 3) * 32);
            }
            {
                const float* wp = sWl + (it + 1) * 32;
#pragma unroll
                for (int o = 0; o < OO; ++o) {
                    const float4 wv = *(const float4*)(wp + o * DD);
#pragma unroll
                    for (int j = 0; j < 4; ++j)
                        acc[j][o] += c0[j].x * wv.x + c0[j].y * wv.y +
                                     c0[j].z * wv.z + c0[j].w * wv.w;
                }
            }
        }

        // 3-level reduction within each 8-lane group, then cross-wave via LDS.
#pragma unroll
        for (int j = 0; j < 4; ++j) {
#pragma unroll
            for (int o = 0; o < OO; ++o) {
                float v = acc[j][o];
                v += __shfl_down(v, 4, 8);
                v += __shfl_down(v, 2, 8);
                v += __shfl_down(v, 1, 8);
                if (l == 0) part[w][j * 8 + g][o] = v;
            }
        }
        __syncthreads();

        // sync#2 (WAR): every block finished reading the u-slab from global
        // before anyone overwrites it with final outputs. Placed late so the
        // gemm overlaps across blocks; only the tiny epilogue is gated.
        if (phase == 1) gg.sync();

        // 32 rows x 10 o = 320 outputs
        for (int idx = tid; idx < 32 * OO; idx += 256) {
            const int row = idx / OO;
            const int o   = idx % OO;
            float v = part[0][row][o] + part[1][row][o] +
                      part[2][row][o] + part[3][row][o];
            if (phase == 0) {
                // u = exp((dot + bias)/O); |arg| < ~0.5 -> max-free exp safe
                Y[((size_t)b * OO + o) * TT + (t0 + row)] =
                    __expf((v + bias[o]) * (1.0f / OO));
            } else {
                Y[((size_t)b * OO + o) * TT + (t0 + row)] = v / zred[o];
            }
        }

        // sync#1 (RAW): all u writes visible grid-wide before phase-1 staging.
        if (phase == 0) gg.sync();
    }
}

// ---------------------------------------------------------------------------
// Fallback path (two launches through d_ws) in case cooperative launch is
// rejected under graph capture. Identical to the previous best kernel.
// ---------------------------------------------------------------------------
template <bool FIRST>
__global__ __launch_bounds__(256) void gemm10_kernel(
    const float* __restrict__ X,
    const float* __restrict__ Wt,
    const float* __restrict__ bias,
    float* __restrict__ Y)
{
    __shared__ float4 sW4[OO * 256];
    __shared__ float  part[4][32][OO];
    __shared__ float  zred[OO];

    const int b   = blockIdx.y;
    const int t0  = blockIdx.x * 32;
    const int tid = threadIdx.x;

    {
        const float4* src = (const float4*)(Wt + (FIRST ? 0 : (size_t)b * OO * TT));
#pragma unroll
        for (int c = 0; c < 10; ++c)
            sW4[c * 256 + tid] = src[c * 256 + tid];
    }
    __syncthreads();

    const int w    = tid >> 6;
    const int lane = tid & 63;
    const int l    = lane & 7;
    const int g    = lane >> 3;
    const int dofs = w * 256 + l * 4;

    if (!FIRST) {
#pragma unroll
        for (int k = 0; k < 3; ++k) {
            const int o = w + 4 * k;
            if (o < OO) {
                float s = 0.f;
#pragma unroll
                for (int q = 0; q < 4; ++q) {
                    const float4 v = sW4[o * 256 + lane * 4 + q];
                    s += v.x + v.y + v.z + v.w;
                }
#pragma unroll
                for (int off = 32; off > 0; off >>= 1)
                    s += __shfl_down(s, off, 64);
                if (lane == 0) zred[o] = s;
            }
        }
    }

    const float* xp[4];
#pragma unroll
    for (int j = 0; j < 4; ++j)
        xp[j] = X + ((size_t)b * TT + t0 + g + 8 * j) * DD + dofs;
    const float* sWl = (const float*)sW4 + dofs;

    float acc[4][OO];
#pragma unroll
    for (int j = 0; j < 4; ++j)
#pragma unroll
        for (int o = 0; o < OO; ++o) acc[j][o] = 0.f;

    float4 x0[4], x1[4];
#pragma unroll
    for (int j = 0; j < 4; ++j) {
        x0[j] = *(const float4*)(xp[j]);
        x1[j] = *(const float4*)(xp[j] + 32);
    }

#pragma unroll 1
    for (int it = 0; it < 8; it += 2) {
        float4 c0[4];
#pragma unroll
        for (int j = 0; j < 4; ++j) c0[j] = x0[j];
        if (it < 6) {
#pragma unroll
            for (int j = 0; j < 4; ++j)
                x0[j] = *(const float4*)(xp[j] + (it + 2) * 32);
        }
        {
            const float* wp = sWl + it * 32;
#pragma unroll
            for (int o = 0; o < OO; ++o) {
                const float4 wv = *(const float4*)(wp + o * DD);
#pragma unroll
                for (int j = 0; j < 4; ++j)
                    acc[j][o] += c0[j].x * wv.x + c0[j].y * wv.y +
                                 c0[j].z * wv.z + c0[j].w * wv.w;
            }
        }
#pragma unroll
        for (int j = 0; j < 4; ++j) c0[j] = x1[j];
        if (it < 5) {
#pragma unroll
            for (int j = 0; j < 4; ++j)
                x1[j] = *(const float4*)(xp[j] + (it + 3) * 32);
        }
        {
            const float* wp = sWl + (it + 1) * 32;
#pragma unroll
            for (int o = 0; o < OO; ++o) {
                const float4 wv = *(const float4*)(wp + o * DD);
#pragma unroll
                for (int j = 0; j < 4; ++j)
                    acc[j][o] += c0[j].x * wv.x + c0[j].y * wv.y +
                                 c0[j].z * wv.z + c0[j].w * wv.w;
            }
        }
    }

#pragma unroll
    for (int j = 0; j < 4; ++j) {
#pragma unroll
        for (int o = 0; o < OO; ++o) {
            float v = acc[j][o];
            v += __shfl_down(v, 4, 8);
            v += __shfl_down(v, 2, 8);
            v += __shfl_down(v, 1, 8);
            if (l == 0) part[w][j * 8 + g][o] = v;
        }
    }
    __syncthreads();

    for (int idx = tid; idx < 32 * OO; idx += 256) {
        const int row = idx / OO;
        const int o   = idx % OO;
        float v = part[0][row][o] + part[1][row][o] +
                  part[2][row][o] + part[3][row][o];
        if (FIRST) {
            Y[((size_t)b * OO + o) * TT + (t0 + row)] =
                __expf((v + bias[o]) * (1.0f / OO));
        } else {
            Y[((size_t)b * OO + o) * TT + (t0 + row)] = v / zred[o];
        }
    }
}

extern "C" void kernel_launch(void* const* d_in, const int* in_sizes, int n_in,
                              void* d_out, int out_size, void* d_ws, size_t ws_size,
                              hipStream_t stream)
{
    const float* logits = (const float*)d_in[0];
    // d_in[1] = decision — unused by the forward math
    const float* W    = (const float*)d_in[2];
    const float* bias = (const float*)d_in[3];
    float* out = (float*)d_out;

    dim3 grid(TT / 32, BB);
    dim3 block(256);

    void* args[] = { (void*)&logits, (void*)&W, (void*)&bias, (void*)&out };
    hipError_t err = hipLaunchCooperativeKernel(
        (const void*)fused_kernel, grid, block, args, 0, stream);

    if (err != hipSuccess) {
        // Cooperative launch unavailable (e.g. capture restriction):
        // fall back to the proven two-kernel path through the workspace.
        (void)hipGetLastError();
        float* u = (float*)d_ws;  // B*O*T floats = 655 KB
        gemm10_kernel<true><<<grid, block, 0, stream>>>(logits, W, bias, u);
        gemm10_kernel<false><<<grid, block, 0, stream>>>(logits, u, nullptr, out);
    }
}

// Round 2
// 129.175 us; speedup vs baseline: 1.7523x; 1.7523x over previous
//
#include <hip/hip_runtime.h>

// Problem constants (reference: B,T,D,O = 16,1024,1024,10; T==D required)
#define BB 16
#define TT 1024
#define DD 1024
#define OO 10
#define ROWS 16   // t-rows per block (was 32)

// ---------------------------------------------------------------------------
// R14 (this): two-kernel structure retained (R15 coop fusion REFUTED: grid.sync
// costs ~45 us each on MI355X — cross-XCD flush + spin; fused ran 130 us vs 39.
// Also measured: the 2x41 us 256MiB ws poison fills are UNCONDITIONAL — they
// remain even if d_ws is never touched. 82 us/iter is a harness floor; only
// the ~39 us of gemm time is addressable).
//
// Change vs 120.3-us baseline: access-footprint + occupancy.
//  - 16 lanes per row (l=lane&15, g=lane>>4): each wave-load instruction now
//    reads 4 rows x 256 B contiguous (was 8 rows x 128 B). LDS operand
//    broadcast becomes 16 distinct float4 addrs = 2-way bank alias = free.
//  - ROWS=16 blocks, grid 64x16=1024: LDS 43 KB -> 3 blocks/CU = 12 waves/CU
//    (was 2 blocks/8 waves). Regs ~unchanged: acc[4][10] + 8xfloat4 prefetch.
//  - Everything else is the proven R5/R10 body: operand ([o][t4]) in LDS,
//    depth-2 x prefetch, unroll-1 outer, broadcast float4 W reads,
//    4-level shfl dots (width 16) + LDS cross-wave combine, max-free softmax.
//
// Refuted (do not retry): occupancy-hint bounds (R2 spill), per-chunk LDS
// staging barriers (R6), device-barrier fusion (R8, R15), per-block softmax
// fold (R9), non-temporal X loads (R11), depth-4 prefetch (R12), 8-wave
// 512-thread blocks (R13), eliminating d_ws to dodge poison fills (R15).
// ---------------------------------------------------------------------------
template <bool FIRST>
__global__ __launch_bounds__(256) void gemm10_kernel(
    const float* __restrict__ X,     // (B,T,D) logits
    const float* __restrict__ Wt,    // FIRST: W (O,D); else u (B,O,T)
    const float* __restrict__ bias,  // FIRST only
    float* __restrict__ Y)           // FIRST: u (B,O,T); else out (B,O,T)
{
    __shared__ float4 sW4[OO * 256];      // 40 KB operand ([o][t4])
    __shared__ float  part[4][ROWS][OO];  // 2.5 KB
    __shared__ float  zred[OO];           // 40 B (K3: per-batch softmax denom)

    const int b   = blockIdx.y;
    const int t0  = blockIdx.x * ROWS;
    const int tid = threadIdx.x;

    // ---- stage operand -> LDS (2560 float4, contiguous, coalesced) ----
    {
        const float4* src = (const float4*)(Wt + (FIRST ? 0 : (size_t)b * OO * TT));
#pragma unroll
        for (int c = 0; c < 10; ++c)
            sW4[c * 256 + tid] = src[c * 256 + tid];
    }
    __syncthreads();

    const int w    = tid >> 6;       // wave 0..3 -> d quarter
    const int lane = tid & 63;
    const int l    = lane & 15;      // d-slice within row (16 lanes -> 256 B)
    const int g    = lane >> 4;      // row group 0..3
    const int dofs = w * 256 + l * 4;

    if (!FIRST) {
        // Z[b,o] = sum_t u from the staged slab. Wave w handles o = w+4k.
        // zred visibility at the epilogue is covered by the pre-epilogue
        // __syncthreads.
#pragma unroll
        for (int k = 0; k < 3; ++k) {
            const int o = w + 4 * k;
            if (o < OO) {
                float s = 0.f;
#pragma unroll
                for (int q = 0; q < 4; ++q) {
                    const float4 v = sW4[o * 256 + lane * 4 + q];
                    s += v.x + v.y + v.z + v.w;
                }
#pragma unroll
                for (int off = 32; off > 0; off >>= 1)
                    s += __shfl_down(s, off, 64);
                if (lane == 0) zred[o] = s;
            }
        }
    }

    // Thread's rows: t0 + g + 4j, j = 0..3 (covers 16 rows/block).
    const float* xp[4];
#pragma unroll
    for (int j = 0; j < 4; ++j)
        xp[j] = X + ((size_t)b * TT + t0 + g + 4 * j) * DD + dofs;
    const float* sWl = (const float*)sW4 + dofs;

    float acc[4][OO];
#pragma unroll
    for (int j = 0; j < 4; ++j)
#pragma unroll
        for (int o = 0; o < OO; ++o) acc[j][o] = 0.f;

    // 2-deep prefetch of the logits slices (it walks 4 x 64-float chunks)
    float4 x0[4], x1[4];
#pragma unroll
    for (int j = 0; j < 4; ++j) {
        x0[j] = *(const float4*)(xp[j]);
        x1[j] = *(const float4*)(xp[j] + 64);
    }

#pragma unroll 1
    for (int it = 0; it < 4; it += 2) {
        float4 c0[4];
#pragma unroll
        for (int j = 0; j < 4; ++j) c0[j] = x0[j];
        if (it < 2) {
#pragma unroll
            for (int j = 0; j < 4; ++j)
                x0[j] = *(const float4*)(xp[j] + (it + 2) * 64);
        }
        {
            const float* wp = sWl + it * 64;
#pragma unroll
            for (int o = 0; o < OO; ++o) {
                const float4 wv = *(const float4*)(wp + o * DD);
#pragma unroll
                for (int j = 0; j < 4; ++j)
                    acc[j][o] += c0[j].x * wv.x + c0[j].y * wv.y +
                                 c0[j].z * wv.z + c0[j].w * wv.w;
            }
        }
#pragma unroll
        for (int j = 0; j < 4; ++j) c0[j] = x1[j];
        if (it < 1) {
#pragma unroll
            for (int j = 0; j < 4; ++j)
                x1[j] = *(const float4*)(xp[j] + (it + 3) * 64);
        }
        {
            const float* wp = sWl + (it + 1) * 64;
#pragma unroll
            for (int o = 0; o < OO; ++o) {
                const float4 wv = *(const float4*)(wp + o * DD);
#pragma unroll
                for (int j = 0; j < 4; ++j)
                    acc[j][o] += c0[j].x * wv.x + c0[j].y * wv.y +
                                 c0[j].z * wv.z + c0[j].w * wv.w;
            }
        }
    }

    // 4-level reduction within each 16-lane group, then cross-wave via LDS.
#pragma unroll
    for (int j = 0; j < 4; ++j) {
#pragma unroll
        for (int o = 0; o < OO; ++o) {
            float v = acc[j][o];
            v += __shfl_down(v, 8, 16);
            v += __shfl_down(v, 4, 16);
            v += __shfl_down(v, 2, 16);
            v += __shfl_down(v, 1, 16);
            if (l == 0) part[w][g + 4 * j][o] = v;
        }
    }
    __syncthreads();

    // 16 rows x 10 o = 160 outputs
    if (tid < ROWS * OO) {
        const int row = tid / OO;
        const int o   = tid % OO;
        float v = part[0][row][o] + part[1][row][o] +
                  part[2][row][o] + part[3][row][o];
        if (FIRST) {
            // u = exp((dot + bias)/O); |arg| < ~0.5 -> max-free exp is safe
            Y[((size_t)b * OO + o) * TT + (t0 + row)] =
                __expf((v + bias[o]) * (1.0f / OO));
        } else {
            Y[((size_t)b * OO + o) * TT + (t0 + row)] = v / zred[o];
        }
    }
}

extern "C" void kernel_launch(void* const* d_in, const int* in_sizes, int n_in,
                              void* d_out, int out_size, void* d_ws, size_t ws_size,
                              hipStream_t stream)
{
    const float* logits = (const float*)d_in[0];
    // d_in[1] = decision — unused by the forward math
    const float* W    = (const float*)d_in[2];
    const float* bias = (const float*)d_in[3];
    float* out = (float*)d_out;
    float* u   = (float*)d_ws;      // B*O*T floats = 2.62 MB

    dim3 grid(TT / ROWS, BB);
    // K1: u = exp((X.W^T + b)/O)   (kernel boundary = fence)
    gemm10_kernel<true><<<grid, 256, 0, stream>>>(logits, W, bias, u);
    // K3: Z computed in-block from the staged slab; out = (X.u) / Z
    gemm10_kernel<false><<<grid, 256, 0, stream>>>(logits, u, nullptr, out);
}

// Round 3
// 119.400 us; speedup vs baseline: 1.8958x; 1.0819x over previous
//
#include <hip/hip_runtime.h>

// Problem constants (reference: B,T,D,O = 16,1024,1024,10; T==D required)
#define BB 16
#define TT 1024
#define DD 1024
#define OO 10
#define ROWS 64   // t-rows per block (R16: 2x amortization of per-block costs)

// ---------------------------------------------------------------------------
// R16 (this): ROWS=64, 512-thread 8-wave blocks, grid 16x16=256 = 1 block/CU.
// Per-wave geometry is the UNCHANGED proven R5/R10 body (8-lane groups,
// 8 rows x 128B slices, depth-2 prefetch, unroll-1, broadcast float4 operand
// reads from LDS, 3-level shfl + LDS cross-wave combine). Waves 0-3 handle
// rows 0-31, waves 4-7 rows 32-63. Mechanism: per-CU staging burst halves
// (40KB vs 80KB), per-block barrier/epilogue/tail amortized 2x, occupancy
// unchanged (8 waves/CU).
//
// Measured context: 2x41us 256MiB ws poison fills are UNCONDITIONAL (present
// even when d_ws untouched) -> 82us harness floor; only ~39us gemm is
// addressable. Pass2 (X from L3) runs same 19.5us as pass1 (X from HBM) ->
// limiter is NOT the memory source; chunk-size theory double-refuted (R14:
// 256B chunks + ROWS=16 regressed to 23.5us/pass via doubled per-block
// overhead; occupancy 12 waves/CU did not help).
//
// Refuted (do not retry): occupancy-hint bounds (R2 spill), per-chunk LDS
// staging barriers (R6), device-barrier fusion (R8, R15: grid.sync ~45us on
// MI355X), per-block softmax fold (R9), non-temporal X loads (R11), depth-4
// prefetch (R12), 8-wave blocks at ROWS=32 with split geometry (R13),
// 16-lane/256B chunks + ROWS=16 (R14), eliminating d_ws (R15: fills stay).
// ---------------------------------------------------------------------------
template <bool FIRST>
__global__ __launch_bounds__(512) void gemm10_kernel(
    const float* __restrict__ X,     // (B,T,D) logits
    const float* __restrict__ Wt,    // FIRST: W (O,D); else u (B,O,T)
    const float* __restrict__ bias,  // FIRST only
    float* __restrict__ Y)           // FIRST: u (B,O,T); else out (B,O,T)
{
    __shared__ float4 sW4[OO * 256];      // 40 KB operand ([o][t4])
    __shared__ float  part[4][ROWS][OO];  // 10 KB
    __shared__ float  zred[OO];           // 40 B (pass2: softmax denom)

    const int b   = blockIdx.y;
    const int t0  = blockIdx.x * ROWS;
    const int tid = threadIdx.x;          // 0..511

    // ---- stage operand -> LDS (2560 float4, contiguous, coalesced) ----
    {
        const float4* src = (const float4*)(Wt + (FIRST ? 0 : (size_t)b * OO * TT));
#pragma unroll
        for (int c = 0; c < 5; ++c)
            sW4[c * 512 + tid] = src[c * 512 + tid];
    }
    __syncthreads();

    const int wv8  = tid >> 6;       // wave 0..7
    const int w    = wv8 & 3;        // d quarter
    const int half = wv8 >> 2;       // row half (0: rows 0-31, 1: rows 32-63)
    const int lane = tid & 63;
    const int l    = lane & 7;       // d-slice within row (8 lanes x 16B)
    const int g    = lane >> 3;      // row group 0..7
    const int dofs = w * 256 + l * 4;
    const int rb   = half * 32;

    if (!FIRST) {
        // Z[b,o] = sum_t u from the staged slab. Wave wv8 handles o = wv8+8k.
        // zred visibility at the epilogue is covered by the pre-epilogue
        // __syncthreads.
#pragma unroll
        for (int k = 0; k < 2; ++k) {
            const int o = wv8 + 8 * k;
            if (o < OO) {
                float s = 0.f;
#pragma unroll
                for (int q = 0; q < 4; ++q) {
                    const float4 v = sW4[o * 256 + lane * 4 + q];
                    s += v.x + v.y + v.z + v.w;
                }
#pragma unroll
                for (int off = 32; off > 0; off >>= 1)
                    s += __shfl_down(s, off, 64);
                if (lane == 0) zred[o] = s;
            }
        }
    }

    // Thread's rows: t0 + rb + g + 8j, j = 0..3 (covers this half's 32 rows).
    const float* xp[4];
#pragma unroll
    for (int j = 0; j < 4; ++j)
        xp[j] = X + ((size_t)b * TT + t0 + rb + g + 8 * j) * DD + dofs;
    const float* sWl = (const float*)sW4 + dofs;

    float acc[4][OO];
#pragma unroll
    for (int j = 0; j < 4; ++j)
#pragma unroll
        for (int o = 0; o < OO; ++o) acc[j][o] = 0.f;

    // 2-deep prefetch of the logits slices
    float4 x0[4], x1[4];
#pragma unroll
    for (int j = 0; j < 4; ++j) {
        x0[j] = *(const float4*)(xp[j]);
        x1[j] = *(const float4*)(xp[j] + 32);
    }

#pragma unroll 1
    for (int it = 0; it < 8; it += 2) {
        float4 c0[4];
#pragma unroll
        for (int j = 0; j < 4; ++j) c0[j] = x0[j];
        if (it < 6) {
#pragma unroll
            for (int j = 0; j < 4; ++j)
                x0[j] = *(const float4*)(xp[j] + (it + 2) * 32);
        }
        {
            const float* wp = sWl + it * 32;
#pragma unroll
            for (int o = 0; o < OO; ++o) {
                const float4 wv = *(const float4*)(wp + o * DD);
#pragma unroll
                for (int j = 0; j < 4; ++j)
                    acc[j][o] += c0[j].x * wv.x + c0[j].y * wv.y +
                                 c0[j].z * wv.z + c0[j].w * wv.w;
            }
        }
#pragma unroll
        for (int j = 0; j < 4; ++j) c0[j] = x1[j];
        if (it < 5) {
#pragma unroll
            for (int j = 0; j < 4; ++j)
                x1[j] = *(const float4*)(xp[j] + (it + 3) * 32);
        }
        {
            const float* wp = sWl + (it + 1) * 32;
#pragma unroll
            for (int o = 0; o < OO; ++o) {
                const float4 wv = *(const float4*)(wp + o * DD);
#pragma unroll
                for (int j = 0; j < 4; ++j)
                    acc[j][o] += c0[j].x * wv.x + c0[j].y * wv.y +
                                 c0[j].z * wv.z + c0[j].w * wv.w;
            }
        }
    }

    // 3-level reduction within each 8-lane group, then cross-wave via LDS.
    // Row halves don't collide: half 0 writes rows 0-31, half 1 rows 32-63.
#pragma unroll
    for (int j = 0; j < 4; ++j) {
#pragma unroll
        for (int o = 0; o < OO; ++o) {
            float v = acc[j][o];
            v += __shfl_down(v, 4, 8);
            v += __shfl_down(v, 2, 8);
            v += __shfl_down(v, 1, 8);
            if (l == 0) part[w][rb + j * 8 + g][o] = v;
        }
    }
    __syncthreads();

    // 64 rows x 10 o = 640 outputs over 512 threads
    for (int idx = tid; idx < ROWS * OO; idx += 512) {
        const int row = idx / OO;
        const int o   = idx % OO;
        float v = part[0][row][o] + part[1][row][o] +
                  part[2][row][o] + part[3][row][o];
        if (FIRST) {
            // u = exp((dot + bias)/O); |arg| < ~0.5 -> max-free exp is safe
            Y[((size_t)b * OO + o) * TT + (t0 + row)] =
                __expf((v + bias[o]) * (1.0f / OO));
        } else {
            Y[((size_t)b * OO + o) * TT + (t0 + row)] = v / zred[o];
        }
    }
}

extern "C" void kernel_launch(void* const* d_in, const int* in_sizes, int n_in,
                              void* d_out, int out_size, void* d_ws, size_t ws_size,
                              hipStream_t stream)
{
    const float* logits = (const float*)d_in[0];
    // d_in[1] = decision — unused by the forward math
    const float* W    = (const float*)d_in[2];
    const float* bias = (const float*)d_in[3];
    float* out = (float*)d_out;
    float* u   = (float*)d_ws;      // B*O*T floats = 655 KB

    dim3 grid(TT / ROWS, BB);       // (16, 16) = 256 blocks = 1/CU
    // K1: u = exp((X.W^T + b)/O)   (kernel boundary = fence)
    gemm10_kernel<true><<<grid, 512, 0, stream>>>(logits, W, bias, u);
    // K3: Z computed in-block from the staged slab; out = (X.u) / Z
    gemm10_kernel<false><<<grid, 512, 0, stream>>>(logits, u, nullptr, out);
}